// Round 18
// baseline (97.328 us; speedup 1.0000x reference)
//
#include <hip/hip_runtime.h>

#define T_LEN  1048576
#define NROWS  32
#define NTAPS  128
#define N2     32
#define BLOCK  256
#define NCH    11             /* K chunks of 16: k = m + 129 - 16c - s */
#define BPR    32             /* blocks per row */
#define SEGS   4              /* segments per wave */
#define W_SEG  2048           /* outputs per segment (2 MFMA tiles) */
#define W_Q4   548            /* float4 loads per segment (2192 elems) */
#define XH_W_BYTES 4416       /* 276 padded 16B chunks; epi aliases bytes 0..4095 */
#define SMEM_BYTES (4 * XH_W_BYTES)   /* 17664 */

typedef __attribute__((ext_vector_type(8)))  _Float16 half8;
typedef __attribute__((ext_vector_type(2)))  __fp16   fp16x2;
typedef __attribute__((ext_vector_type(16))) float    f32x16;
typedef __attribute__((ext_vector_type(4)))  float    f32x4;

__device__ __forceinline__ int swz16(int q) { return q ^ ((q >> 3) & 7); }

// ---- kernel 1: impulse response h[0..127] (+D at 0); fp16 Toeplitz A-frags ----
// A_c[m,s] = h[m + 129 - 16c - s], lane=(m=lane&31, g=lane>>5), s=8g+i
__global__ __launch_bounds__(NTAPS) void ssm_taps(
    const float* __restrict__ w_real, const float* __restrict__ w_imag,
    const float* __restrict__ log_dt,
    const float* __restrict__ C_real, const float* __restrict__ C_imag,
    const float* __restrict__ B_real, const float* __restrict__ B_imag,
    const float* __restrict__ Dp, float* __restrict__ ws) {
  __shared__ float hsh[NTAPS];
  const int k = threadIdx.x;
  const float dt = expf(log_dt[0]);
  const float kf = (float)k;
  float acc = 0.f;
  for (int n = 0; n < N2; ++n) {
    const float a  = dt * w_real[n];
    const float b  = dt * w_imag[n];
    const float cr = C_real[n], ci = C_imag[n];
    const float br = B_real[n], bi = B_imag[n];
    const float coef_r = cr * br - ci * bi;
    const float coef_i = cr * bi + ci * br;
    const float e = expf(a * kf);
    float s, c;
    sincosf(b * kf, &s, &c);
    acc += e * (coef_r * c - coef_i * s);
  }
  if (k == 0) acc += Dp[0];
  ws[k]  = acc;                              // plain h (exact tail)
  hsh[k] = acc;
  __syncthreads();
  if (k < 64) {
    _Float16* AH = (_Float16*)(ws + NTAPS);
    const int m = k & 31, g = k >> 5;
    for (int c = 0; c < NCH; ++c)
      for (int i = 0; i < 8; ++i) {
        const int idx = m + 129 - 16 * c - 8 * g - i;
        const float v = (idx >= 0 && idx < NTAPS) ? hsh[idx] : 0.f;
        AH[(c * 64 + k) * 8 + i] = (_Float16)v;   // RNE
      }
  }
}

// ---- kernel 2: persistent pipelined waves, zero barriers in hot path.
//      Each wave: 4 segments x 2048 outputs. Loads for s+1 fly in registers
//      under compute/epi/store of s; single wave-private LDS buffer (epi
//      aliases dead stage region; same-wave LDS ops are in-order). ----
__global__ __launch_bounds__(BLOCK, 4) void ssm_conv(
    const float* __restrict__ x, const float* __restrict__ ws,
    float* __restrict__ out) {
  __shared__ __align__(16) unsigned char smem[SMEM_BYTES];
  const int tid  = threadIdx.x;
  const int lane = tid & 63;
  const int wid  = tid >> 6;
  const int p    = lane & 31, g = lane >> 5;
  const int row  = blockIdx.x >> 5;          // 32 blocks per row
  const int jb   = blockIdx.x & 31;
  const int WB   = jb * (4 * SEGS * W_SEG) + wid * (SEGS * W_SEG);
  const float* __restrict__ xrow = x + (size_t)row * T_LEN;
  float* __restrict__ orow = out + (size_t)row * T_LEN;

  char*  xw   = (char*)smem + wid * XH_W_BYTES;   // wave-private stage
  float* ebuf = (float*)xw;                        // epi aliases stage

  float4 xf[9];                              // in-flight segment loads

  // issue segment-0 loads FIRST (longest latency)
#pragma unroll
  for (int j = 0; j < 9; ++j) {
    const int q4 = lane + 64 * j;
    if (j < 8 || lane < W_Q4 - 512) {
      int gfi = WB - 256 + 4 * q4;           // clamp left edge (tail re-fixes)
      gfi = gfi < 0 ? 0 : gfi;
      xf[j] = *(const float4*)(xrow + gfi);
    }
  }
  // A fragments -> VGPRs (L2-hot) while x loads fly
  half8 A[NCH];
  const half8* __restrict__ wsA = (const half8*)(ws + NTAPS);
#pragma unroll
  for (int c = 0; c < NCH; ++c) A[c] = wsA[c * 64 + lane];

  // stage segment 0
#pragma unroll
  for (int j = 0; j < 9; ++j) {
    const int q4 = lane + 64 * j;
    if (j < 8 || lane < W_Q4 - 512) {
      const fp16x2 a = __builtin_amdgcn_cvt_pkrtz(xf[j].x, xf[j].y);
      const fp16x2 b = __builtin_amdgcn_cvt_pkrtz(xf[j].z, xf[j].w);
      uint2 w;
      w.x = __builtin_bit_cast(unsigned, a);
      w.y = __builtin_bit_cast(unsigned, b);
      *(uint2*)(xw + swz16(q4 >> 1) * 16 + (q4 & 1) * 8) = w;
    }
  }

  const int qb = 4 * p + g;                  // lane's fp16-chunk base
#pragma unroll
  for (int s = 0; s < SEGS; ++s) {
    const int W0 = WB + s * W_SEG;

    // (1) issue next segment's loads — they fly under compute+epi+stores
    if (s + 1 < SEGS) {
#pragma unroll
      for (int j = 0; j < 9; ++j) {
        const int q4 = lane + 64 * j;
        if (j < 8 || lane < W_Q4 - 512) {
          const int gfi = W0 + W_SEG - 256 + 4 * q4;   // never <0 for s>=0
          xf[j] = *(const float4*)(xrow + gfi);
        }
      }
    }

    // (2) compute: 2 tiles x 11 x { ds_read_b128 + MFMA }
    f32x16 acc0 = {}, acc1 = {};
#pragma unroll
    for (int c = 0; c < NCH; ++c) {
      const half8 B0 = *(const half8*)(xw + swz16(qb + 2 * c) * 16);
      acc0 = __builtin_amdgcn_mfma_f32_32x32x16_f16(A[c], B0, acc0, 0, 0, 0);
      const half8 B1 = *(const half8*)(xw + swz16(qb + 128 + 2 * c) * 16);
      acc1 = __builtin_amdgcn_mfma_f32_32x32x16_f16(A[c], B1, acc1, 0, 0, 0);
    }

    // (3) epilogue per tile into the dead stage region: [32 pc][8 qm] quad
    // grid, XOR-swizzled -> conflict-free; 4 coalesced NT stores per tile.
#pragma unroll
    for (int tt = 0; tt < 2; ++tt) {
      const f32x16& acc = tt ? acc1 : acc0;
#pragma unroll
      for (int k = 0; k < 4; ++k) {          // quad r=4k..4k+3: m=8k+4g+j, col p
        const int q = p * 8 + 2 * k + g;
        float4 v;
        v.x = acc[4 * k];     v.y = acc[4 * k + 1];
        v.z = acc[4 * k + 2]; v.w = acc[4 * k + 3];
        *(float4*)(ebuf + (q ^ (p & 7)) * 4) = v;
      }
      float* __restrict__ obase = orow + W0 + tt * 1024;
#pragma unroll
      for (int pp = 0; pp < 4; ++pp) {
        const int o  = 4 * lane + 256 * pp;  // outputs o..o+3 (o = 32*pc + m)
        const int pc = o >> 5;
        const int q  = pc * 8 + (lane & 7);
        const f32x4 v = *(const f32x4*)(ebuf + (q ^ (pc & 7)) * 4);
        __builtin_nontemporal_store(v, (f32x4*)(obase + o));
      }
    }

    // (4) stage segment s+1 (in-order after epi reads; vmcnt mostly drained)
    if (s + 1 < SEGS) {
#pragma unroll
      for (int j = 0; j < 9; ++j) {
        const int q4 = lane + 64 * j;
        if (j < 8 || lane < W_Q4 - 512) {
          const fp16x2 a = __builtin_amdgcn_cvt_pkrtz(xf[j].x, xf[j].y);
          const fp16x2 b = __builtin_amdgcn_cvt_pkrtz(xf[j].z, xf[j].w);
          uint2 w;
          w.x = __builtin_bit_cast(unsigned, a);
          w.y = __builtin_bit_cast(unsigned, b);
          *(uint2*)(xw + swz16(q4 >> 1) * 16 + (q4 & 1) * 8) = w;
        }
      }
    }
  }

  // merged exact fp32 tail: first block of each row rewrites n in [0,254)
  if (jb == 0) {
    __syncthreads();
    const float* __restrict__ h = ws;
    if (tid < 254) {
      float a = 0.f;
      if (tid < 127) {                       // circular wraparound region
        for (int k = tid + 1; k < NTAPS; ++k)
          a += h[k] * xrow[T_LEN + tid - k];
      } else {                               // causal with zero left-pad
        for (int k = 0; k <= tid - 127; ++k)
          a += h[k] * xrow[tid - 127 - k];
      }
      orow[tid] = a;
    }
  }
}

extern "C" void kernel_launch(void* const* d_in, const int* in_sizes, int n_in,
                              void* d_out, int out_size, void* d_ws, size_t ws_size,
                              hipStream_t stream) {
  const float* x      = (const float*)d_in[0];
  const float* w_real = (const float*)d_in[1];
  const float* w_imag = (const float*)d_in[2];
  const float* log_dt = (const float*)d_in[3];
  const float* C_real = (const float*)d_in[4];
  const float* C_imag = (const float*)d_in[5];
  const float* B_real = (const float*)d_in[6];
  const float* B_imag = (const float*)d_in[7];
  const float* Dp     = (const float*)d_in[8];
  float* out = (float*)d_out;
  float* ws  = (float*)d_ws;   // 128 f32 h + NCH*64*8 fp16 A-frags = 11.8 KB

  ssm_taps<<<1, NTAPS, 0, stream>>>(w_real, w_imag, log_dt,
                                    C_real, C_imag, B_real, B_imag, Dp, ws);
  ssm_conv<<<NROWS * BPR, BLOCK, 0, stream>>>(x, ws, out);
}

// Round 19
// 69.568 us; speedup vs baseline: 1.3990x; 1.3990x over previous
//
#include <hip/hip_runtime.h>

#define T_LEN  1048576
#define NROWS  32
#define NTAPS  128
#define N2     32
#define BLOCK  256
#define NCH    11             /* K chunks of 16: k = m + 129 - 16c - s */
#define W_OUT  2048           /* outputs per wave (2 MFMA tiles) */
#define BPR    128            /* blocks per row */
#define W_Q4   548            /* float4 loads per wave (2192 elems) */
#define XH_W_BYTES 4416       /* 276 padded 16B chunks; epi aliases bytes 0..4095 */
#define SMEM_BYTES (4 * XH_W_BYTES)   /* 17664 -> 8 blocks/CU (thread-capped) */

typedef __attribute__((ext_vector_type(8)))  _Float16 half8;
typedef __attribute__((ext_vector_type(2)))  __fp16   fp16x2;
typedef __attribute__((ext_vector_type(16))) float    f32x16;
typedef __attribute__((ext_vector_type(4)))  float    f32x4;

__device__ __forceinline__ int swz16(int q) { return q ^ ((q >> 3) & 7); }

// ---- kernel 1: impulse response h[0..127] (+D at 0); fp16 Toeplitz A-frags ----
// A_c[m,s] = h[m + 129 - 16c - s], lane=(m=lane&31, g=lane>>5), s=8g+i
__global__ __launch_bounds__(NTAPS) void ssm_taps(
    const float* __restrict__ w_real, const float* __restrict__ w_imag,
    const float* __restrict__ log_dt,
    const float* __restrict__ C_real, const float* __restrict__ C_imag,
    const float* __restrict__ B_real, const float* __restrict__ B_imag,
    const float* __restrict__ Dp, float* __restrict__ ws) {
  __shared__ float hsh[NTAPS];
  const int k = threadIdx.x;
  const float dt = expf(log_dt[0]);
  const float kf = (float)k;
  float acc = 0.f;
  for (int n = 0; n < N2; ++n) {
    const float a  = dt * w_real[n];
    const float b  = dt * w_imag[n];
    const float cr = C_real[n], ci = C_imag[n];
    const float br = B_real[n], bi = B_imag[n];
    const float coef_r = cr * br - ci * bi;
    const float coef_i = cr * bi + ci * br;
    const float e = expf(a * kf);
    float s, c;
    sincosf(b * kf, &s, &c);
    acc += e * (coef_r * c - coef_i * s);
  }
  if (k == 0) acc += Dp[0];
  ws[k]  = acc;                              // plain h (exact tail)
  hsh[k] = acc;
  __syncthreads();
  if (k < 64) {
    _Float16* AH = (_Float16*)(ws + NTAPS);
    const int m = k & 31, g = k >> 5;
    for (int c = 0; c < NCH; ++c)
      for (int i = 0; i < 8; ++i) {
        const int idx = m + 129 - 16 * c - 8 * g - i;
        const float v = (idx >= 0 && idx < NTAPS) ? hsh[idx] : 0.f;
        AH[(c * 64 + k) * 8 + i] = (_Float16)v;   // RNE
      }
  }
}

// ---- kernel 2: lean high-occupancy implicit-GEMM FIR, two 32x32 tiles/wave.
//      Barrier-free; inline fp16 staging into wave-private LDS; epilogue
//      aliases the dead stage region; A-frags read in-loop (L1-hot);
//      8 blocks/CU, 32 waves/CU. ----
__global__ __launch_bounds__(BLOCK, 8) void ssm_conv(
    const float* __restrict__ x, const float* __restrict__ ws,
    float* __restrict__ out) {
  __shared__ __align__(16) unsigned char smem[SMEM_BYTES];
  const int tid  = threadIdx.x;
  const int lane = tid & 63;
  const int wid  = tid >> 6;
  const int p    = lane & 31, g = lane >> 5;
  const int row  = blockIdx.x >> 7;          // 128 blocks per row
  const int jb   = blockIdx.x & 127;
  const int W0   = jb * (4 * W_OUT) + wid * W_OUT;   // wave's output base
  const float* __restrict__ xrow = x + (size_t)row * T_LEN;

  char*  xw   = (char*)smem + wid * XH_W_BYTES;      // wave-private stage
  float* ebuf = (float*)xw;                          // epi aliases stage

  // stage wave's 2192-elem window as fp16 (staged e <-> x[W0 - 256 + e]);
  // inline load->cvt->write: no big live register array (spill-safe).
#pragma unroll
  for (int j = 0; j < 9; ++j) {
    const int q4 = lane + 64 * j;            // float4 index within window
    if (q4 < W_Q4) {
      int gfi = W0 - 256 + 4 * q4;           // clamp left edge (tail re-fixes)
      gfi = gfi < 0 ? 0 : gfi;
      const float4 f = *(const float4*)(xrow + gfi);
      const fp16x2 a = __builtin_amdgcn_cvt_pkrtz(f.x, f.y);
      const fp16x2 b = __builtin_amdgcn_cvt_pkrtz(f.z, f.w);
      uint2 w;
      w.x = __builtin_bit_cast(unsigned, a);
      w.y = __builtin_bit_cast(unsigned, b);
      *(uint2*)(xw + swz16(q4 >> 1) * 16 + (q4 & 1) * 8) = w;
    }
  }
  // no barrier: same-wave ds ops are in-order / lgkmcnt-tracked

  // compute: 2 tiles x 11 x { A global load (L1-hot) + ds_read_b128 + MFMA }
  const half8* __restrict__ wsA = (const half8*)(ws + NTAPS);
  const int qb = 4 * p + g;                  // lane's fp16-chunk base
  f32x16 acc0 = {}, acc1 = {};
#pragma unroll
  for (int c = 0; c < NCH; ++c) {
    const half8 Ac = wsA[c * 64 + lane];     // in-loop: keeps VGPR <= 64
    const half8 B0 = *(const half8*)(xw + swz16(qb + 2 * c) * 16);
    acc0 = __builtin_amdgcn_mfma_f32_32x32x16_f16(Ac, B0, acc0, 0, 0, 0);
    const half8 B1 = *(const half8*)(xw + swz16(qb + 128 + 2 * c) * 16);
    acc1 = __builtin_amdgcn_mfma_f32_32x32x16_f16(Ac, B1, acc1, 0, 0, 0);
  }

  // epilogue per tile into the (now dead) stage region: [32 pc][8 qm] quad
  // grid, XOR-swizzled -> conflict-free writes AND reads; 4 coalesced NT
  // dwordx4 stores per tile. Same-wave in-order LDS: epi writes land after
  // all B-reads above.
#pragma unroll
  for (int tt = 0; tt < 2; ++tt) {
    const f32x16& acc = tt ? acc1 : acc0;
#pragma unroll
    for (int k = 0; k < 4; ++k) {            // quad r=4k..4k+3: m=8k+4g+j, col p
      const int q = p * 8 + 2 * k + g;
      float4 v;
      v.x = acc[4 * k];     v.y = acc[4 * k + 1];
      v.z = acc[4 * k + 2]; v.w = acc[4 * k + 3];
      *(float4*)(ebuf + (q ^ (p & 7)) * 4) = v;
    }
    float* __restrict__ obase = out + (size_t)row * T_LEN + W0 + tt * 1024;
#pragma unroll
    for (int pp = 0; pp < 4; ++pp) {
      const int o  = 4 * lane + 256 * pp;    // outputs o..o+3 (o = 32*pc + m)
      const int pc = o >> 5;
      const int q  = pc * 8 + (lane & 7);
      const f32x4 v = *(const f32x4*)(ebuf + (q ^ (pc & 7)) * 4);
      __builtin_nontemporal_store(v, (f32x4*)(obase + o));
    }
  }

  // merged exact fp32 tail: first block of each row rewrites n in [0,254)
  if (jb == 0) {
    __syncthreads();                         // drains this block's stores
    const float* __restrict__ h = ws;
    if (tid < 254) {
      float a = 0.f;
      if (tid < 127) {                       // circular wraparound region
        for (int k = tid + 1; k < NTAPS; ++k)
          a += h[k] * xrow[T_LEN + tid - k];
      } else {                               // causal with zero left-pad
        for (int k = 0; k <= tid - 127; ++k)
          a += h[k] * xrow[tid - 127 - k];
      }
      out[(size_t)row * T_LEN + tid] = a;
    }
  }
}

extern "C" void kernel_launch(void* const* d_in, const int* in_sizes, int n_in,
                              void* d_out, int out_size, void* d_ws, size_t ws_size,
                              hipStream_t stream) {
  const float* x      = (const float*)d_in[0];
  const float* w_real = (const float*)d_in[1];
  const float* w_imag = (const float*)d_in[2];
  const float* log_dt = (const float*)d_in[3];
  const float* C_real = (const float*)d_in[4];
  const float* C_imag = (const float*)d_in[5];
  const float* B_real = (const float*)d_in[6];
  const float* B_imag = (const float*)d_in[7];
  const float* Dp     = (const float*)d_in[8];
  float* out = (float*)d_out;
  float* ws  = (float*)d_ws;   // 128 f32 h + NCH*64*8 fp16 A-frags = 11.8 KB

  ssm_taps<<<1, NTAPS, 0, stream>>>(w_real, w_imag, log_dt,
                                    C_real, C_imag, B_real, B_imag, Dp, ws);
  ssm_conv<<<NROWS * BPR, BLOCK, 0, stream>>>(x, ws, out);
}